// Round 4
// baseline (8455.825 us; speedup 1.0000x reference)
//
#include <hip/hip_runtime.h>
#include <hip/hip_bf16.h>

#define B_   128
#define S_   512
#define I_   256
#define H_   256
#define G4   1024   // 4*H

// Journal R4 (first real counters, R3 run: total 6002us, scan 5504us,
// VALUBusy 6.6%, Occ 3%, HBM 0.3%):
//   Scan was latency-starved: 256-thr WGs = 1 wave/SIMD, no TLP, per-k L2
//   loads serialized. This round: 512-thr WGs (2 waves/SIMD), thread=(unit,
//   batch) owns all 4 gates (c in reg, no gate exchange), k-blocked dot
//   (ds_read_b128 h + 4x float4 U + 16 FMA per iter, unroll 8), __expf
//   activations. Structure/floor: 64 WGs x 2 batches, U from XCD-L2 every
//   step => max(VALU 1.7us, L2 1.86us)/step ~ 1ms scan.

__device__ __forceinline__ float masked_noise(float u, float n, float r) {
    // masking.forward, mask_type='signed'  (EPS = 1e-8)
    float z = (u / (n + 1e-8f) + 1.0f) * 0.5f;
    float m = floorf(z + r);
    m = fminf(fmaxf(m, 0.0f), 1.0f);
    return n * (2.0f * m - 1.0f);
}

__device__ __forceinline__ float sigmoid_f(float x) {
    return 1.0f / (1.0f + __expf(-x));   // x->-inf: exp=inf, 1/inf=0: safe
}
__device__ __forceinline__ float tanh_f(float x) {
    float ax = fabsf(x);
    float t = __expf(-2.0f * ax);        // in (0,1], no overflow
    float r = (1.0f - t) / (1.0f + t);
    return copysignf(r, x);
}

// ---------------- prep: actual_W / actual_U, gate-interleaved ----------------
// out layout: a[k*1024 + j*4 + g] = orig[k*1024 + g*256 + j]
// (column permutation; GEMM treats columns opaquely, scan reads float4)
__global__ __launch_bounds__(256) void prep_kernel(
    const float* __restrict__ W,  const float* __restrict__ uW,
    const float* __restrict__ nW, const float* __restrict__ rW,
    const float* __restrict__ U,  const float* __restrict__ uU,
    const float* __restrict__ nU, const float* __restrict__ rU,
    float* __restrict__ aW4, float* __restrict__ aU4) {
    int idx = blockIdx.x * 256 + threadIdx.x;
    const int n = I_ * G4;  // 262144
    if (idx < n) {
        float v = W[idx] + masked_noise(uW[idx], nW[idx], rW[idx]);
        int k = idx >> 10, col = idx & 1023;
        int g = col >> 8, j = col & 255;
        aW4[((size_t)(k << 8) + j) * 4 + g] = v;
    } else {
        int i2 = idx - n;
        float v = U[i2] + masked_noise(uU[i2], nU[i2], rU[i2]);
        int k = i2 >> 10, col = i2 & 1023;
        int g = col >> 8, j = col & 255;
        aU4[((size_t)(k << 8) + j) * 4 + g] = v;
    }
}

// ---------------- xW = einsum('bsi,ig->sbg'), permuted columns ----------------
// Tile: 128 rows (all b, one s) x 64 cols, K chunks of 64. grid=(16,512).
template<int XW_BF16>
__global__ __launch_bounds__(256) void xw_gemm(
    const float* __restrict__ x, const float* __restrict__ aW4,
    void* __restrict__ xw_out) {
    __shared__ float xs[64][132];  // [kk][row]  (x tile, transposed)
    __shared__ float wt[64][68];   // [kk][col]
    const int tid = threadIdx.x;
    const int tx = tid & 15;        // col group of 4
    const int ty = tid >> 4;        // row group of 8
    const int bx = blockIdx.x;      // N tile (64 cols)
    const int s  = blockIdx.y;      // timestep

    float acc[8][4];
#pragma unroll
    for (int i = 0; i < 8; ++i)
#pragma unroll
        for (int j = 0; j < 4; ++j) acc[i][j] = 0.0f;

    for (int kc = 0; kc < 4; ++kc) {
#pragma unroll
        for (int t = 0; t < 8; ++t) {
            int e = tid + t * 256;           // 0..2047
            int row = e >> 4;                // b
            int kq  = e & 15;                // float4 index along k
            float4 v = *reinterpret_cast<const float4*>(
                &x[((size_t)row * S_ + s) * I_ + kc * 64 + kq * 4]);
            xs[kq * 4 + 0][row] = v.x;
            xs[kq * 4 + 1][row] = v.y;
            xs[kq * 4 + 2][row] = v.z;
            xs[kq * 4 + 3][row] = v.w;
        }
#pragma unroll
        for (int t = 0; t < 4; ++t) {
            int e = tid + t * 256;           // 0..1023
            int kk = e >> 4;
            int cq = e & 15;
            float4 v = *reinterpret_cast<const float4*>(
                &aW4[((size_t)(kc * 64 + kk)) * G4 + bx * 64 + cq * 4]);
            *reinterpret_cast<float4*>(&wt[kk][cq * 4]) = v;
        }
        __syncthreads();

#pragma unroll 8
        for (int kk = 0; kk < 64; ++kk) {
            float4 a0 = *reinterpret_cast<const float4*>(&xs[kk][ty * 8]);
            float4 a1 = *reinterpret_cast<const float4*>(&xs[kk][ty * 8 + 4]);
            float4 bv = *reinterpret_cast<const float4*>(&wt[kk][tx * 4]);
            float a[8] = {a0.x, a0.y, a0.z, a0.w, a1.x, a1.y, a1.z, a1.w};
            float b[4] = {bv.x, bv.y, bv.z, bv.w};
#pragma unroll
            for (int i = 0; i < 8; ++i)
#pragma unroll
                for (int j = 0; j < 4; ++j) acc[i][j] += a[i] * b[j];
        }
        __syncthreads();
    }

#pragma unroll
    for (int i = 0; i < 8; ++i) {
        int row = ty * 8 + i;  // b
        size_t off = ((size_t)s * B_ + row) * G4 + bx * 64 + tx * 4;
        if (XW_BF16) {
            __hip_bfloat16* xwb = (__hip_bfloat16*)xw_out;
            alignas(8) __hip_bfloat16 tmp[4];
#pragma unroll
            for (int j = 0; j < 4; ++j) tmp[j] = __float2bfloat16(acc[i][j]);
            *reinterpret_cast<ushort4*>(&xwb[off]) =
                *reinterpret_cast<const ushort4*>(tmp);
        } else {
            float* xwf = (float*)xw_out;
            float4 v = {acc[i][0], acc[i][1], acc[i][2], acc[i][3]};
            *reinterpret_cast<float4*>(&xwf[off]) = v;
        }
    }
}

// ---------------- sequential LSTM scan ----------------
// 64 blocks x 512 threads (8 waves = 2/SIMD); block owns batches
// {2*bid, 2*bid+1}. Thread (u = tid&255, bb = tid>>8) owns unit u of batch
// bb: computes all 4 gate dots (float4 acc), c/h in registers.
// Per 4-k block: 1 ds_read_b128 (h) + 4 global float4 (U) + 16 FMA.
// TIER: 0 = fp32 xw, 1 = bf16 xw, 2 = fused (recompute x@W per step).
template<int TIER>
__global__ __launch_bounds__(512) void lstm_scan(
    const void* __restrict__ xw_in, const float* __restrict__ aU4,
    const float* __restrict__ aW4, const float* __restrict__ x,
    float* __restrict__ out) {
    const int tid = threadIdx.x;
    const int u   = tid & 255;
    const int bb  = tid >> 8;               // 0 or 1
    const int b   = blockIdx.x * 2 + bb;
    __shared__ float hbuf[2][2][H_];        // [buf][bb][k]
    __shared__ float xsh[2][I_];            // TIER2: x rows for this step

    hbuf[0][bb][u] = 0.0f;
    float c = 0.0f, h = 0.0f;
    __syncthreads();

    const float*          xwf = (const float*)xw_in;
    const __hip_bfloat16* xwb = (const __hip_bfloat16*)xw_in;
    const float* Ub = aU4 + ((size_t)u << 2);   // + k*1024 per row
    const float* Wb = aW4 + ((size_t)u << 2);

    for (int s = 0; s < S_; ++s) {
        const int cur = s & 1;
        float4 acc = {0.f, 0.f, 0.f, 0.f};      // i,f,g,o sums

        if (TIER == 2) {
            xsh[bb][u] = x[((size_t)b * S_ + s) * I_ + u];
            __syncthreads();
        }

#pragma unroll 8
        for (int k4 = 0; k4 < 64; ++k4) {
            float4 h4 = *reinterpret_cast<const float4*>(
                &hbuf[cur][bb][k4 << 2]);
            float4 u0 = *reinterpret_cast<const float4*>(
                &Ub[(size_t)(k4 * 4 + 0) * G4]);
            float4 u1 = *reinterpret_cast<const float4*>(
                &Ub[(size_t)(k4 * 4 + 1) * G4]);
            float4 u2 = *reinterpret_cast<const float4*>(
                &Ub[(size_t)(k4 * 4 + 2) * G4]);
            float4 u3 = *reinterpret_cast<const float4*>(
                &Ub[(size_t)(k4 * 4 + 3) * G4]);
            acc.x += h4.x * u0.x; acc.y += h4.x * u0.y;
            acc.z += h4.x * u0.z; acc.w += h4.x * u0.w;
            acc.x += h4.y * u1.x; acc.y += h4.y * u1.y;
            acc.z += h4.y * u1.z; acc.w += h4.y * u1.w;
            acc.x += h4.z * u2.x; acc.y += h4.z * u2.y;
            acc.z += h4.z * u2.z; acc.w += h4.z * u2.w;
            acc.x += h4.w * u3.x; acc.y += h4.w * u3.y;
            acc.z += h4.w * u3.z; acc.w += h4.w * u3.w;
        }

        float4 xg = {0.f, 0.f, 0.f, 0.f};
        if (TIER == 0) {
            xg = *reinterpret_cast<const float4*>(
                &xwf[((size_t)s * B_ + b) * G4 + (u << 2)]);
        } else if (TIER == 1) {
            ushort4 r = *reinterpret_cast<const ushort4*>(
                &xwb[((size_t)s * B_ + b) * G4 + (u << 2)]);
            xg.x = __uint_as_float((unsigned)r.x << 16);
            xg.y = __uint_as_float((unsigned)r.y << 16);
            xg.z = __uint_as_float((unsigned)r.z << 16);
            xg.w = __uint_as_float((unsigned)r.w << 16);
        } else {
            // fused x@W contribution
#pragma unroll 8
            for (int k4 = 0; k4 < 64; ++k4) {
                float4 x4 = *reinterpret_cast<const float4*>(
                    &xsh[bb][k4 << 2]);
                float4 w0 = *reinterpret_cast<const float4*>(
                    &Wb[(size_t)(k4 * 4 + 0) * G4]);
                float4 w1 = *reinterpret_cast<const float4*>(
                    &Wb[(size_t)(k4 * 4 + 1) * G4]);
                float4 w2 = *reinterpret_cast<const float4*>(
                    &Wb[(size_t)(k4 * 4 + 2) * G4]);
                float4 w3 = *reinterpret_cast<const float4*>(
                    &Wb[(size_t)(k4 * 4 + 3) * G4]);
                xg.x += x4.x * w0.x; xg.y += x4.x * w0.y;
                xg.z += x4.x * w0.z; xg.w += x4.x * w0.w;
                xg.x += x4.y * w1.x; xg.y += x4.y * w1.y;
                xg.z += x4.y * w1.z; xg.w += x4.y * w1.w;
                xg.x += x4.z * w2.x; xg.y += x4.z * w2.y;
                xg.z += x4.z * w2.z; xg.w += x4.z * w2.w;
                xg.x += x4.w * w3.x; xg.y += x4.w * w3.y;
                xg.z += x4.w * w3.z; xg.w += x4.w * w3.w;
            }
        }

        float it = sigmoid_f(acc.x + xg.x);
        float ft = sigmoid_f(acc.y + xg.y);
        float gt = tanh_f(acc.z + xg.z);
        float ot = sigmoid_f(acc.w + xg.w);
        c = ft * c + it * gt;
        h = ot * tanh_f(c);

        out[((size_t)b * S_ + s) * H_ + u] = h;
        hbuf[cur ^ 1][bb][u] = h;
        __syncthreads();
    }

    const size_t HS = (size_t)B_ * S_ * H_;          // 16777216
    const size_t CS = (size_t)B_ * H_;               // 32768
    out[HS + (size_t)b * H_ + u]      = h;
    out[HS + CS + (size_t)b * H_ + u] = c;
}

// ---------------- launch ----------------
extern "C" void kernel_launch(void* const* d_in, const int* in_sizes, int n_in,
                              void* d_out, int out_size, void* d_ws, size_t ws_size,
                              hipStream_t stream) {
    const float* x  = (const float*)d_in[0];
    const float* W  = (const float*)d_in[1];
    const float* U  = (const float*)d_in[2];
    const float* uW = (const float*)d_in[3];
    const float* nW = (const float*)d_in[4];
    const float* rW = (const float*)d_in[5];
    const float* uU = (const float*)d_in[6];
    const float* nU = (const float*)d_in[7];
    const float* rU = (const float*)d_in[8];

    float* ws  = (float*)d_ws;
    float* aW4 = ws;                       // 262144 floats
    float* aU4 = ws + 262144;              // 262144 floats
    void*  xw  = (void*)(ws + 524288);     // S*B*4H elems (fp32 or bf16)

    const size_t xw_elems  = (size_t)S_ * B_ * G4;            // 67108864
    const size_t need_fp32 = (524288 + xw_elems) * 4;         // ~258 MB
    const size_t need_bf16 = 524288 * 4 + xw_elems * 2;       // ~130 MB

    prep_kernel<<<2048, 256, 0, stream>>>(W, uW, nW, rW, U, uU, nU, rU, aW4, aU4);

    dim3 ggrid(16, 512);
    if (ws_size >= need_fp32) {
        xw_gemm<0><<<ggrid, 256, 0, stream>>>(x, aW4, xw);
        lstm_scan<0><<<64, 512, 0, stream>>>(xw, aU4, aW4, x, (float*)d_out);
    } else if (ws_size >= need_bf16) {
        xw_gemm<1><<<ggrid, 256, 0, stream>>>(x, aW4, xw);
        lstm_scan<1><<<64, 512, 0, stream>>>(xw, aU4, aW4, x, (float*)d_out);
    } else {
        lstm_scan<2><<<64, 512, 0, stream>>>(nullptr, aU4, aW4, x, (float*)d_out);
    }
}

// Round 5
// 4710.822 us; speedup vs baseline: 1.7950x; 1.7950x over previous
//
#include <hip/hip_runtime.h>
#include <hip/hip_bf16.h>

#define B_   128
#define S_   512
#define I_   256
#define H_   256
#define G4   1024   // 4*H

// Journal R5. History: R3 scan 5504us (256thr, 1 wave/SIMD, latency-starved,
// VALUBusy 6.6%); R4 REGRESSED 7972us (512thr (u,bb) layout read U twice/WG,
// VGPR=44 -> ~8 loads in flight, VALUBusy 5.1%).
// R5: 64 WGs x 1024 thr (16 waves, 4/SIMD). Thread (u=tid&255, kq=tid>>8)
// accumulates partial gate sums for BOTH batches over its 64-row k-quarter:
// U read ONCE per WG per step, 64 independent float4 loads/thread/step,
// 8 FMA each. Partials via dbuf scalar LDS [3][8][256] (conflict-free),
// kq==0 reduces + activations + owns c/h. 2 barriers/step.
// Floor: VALU ~2.2us, L2 1.9-3.7us per step -> scan ~1.3-1.9ms.

__device__ __forceinline__ float masked_noise(float u, float n, float r) {
    // masking.forward, mask_type='signed'  (EPS = 1e-8)
    float z = (u / (n + 1e-8f) + 1.0f) * 0.5f;
    float m = floorf(z + r);
    m = fminf(fmaxf(m, 0.0f), 1.0f);
    return n * (2.0f * m - 1.0f);
}

__device__ __forceinline__ float sigmoid_f(float x) {
    return 1.0f / (1.0f + __expf(-x));   // x->-inf: exp=inf, 1/inf=0: safe
}
__device__ __forceinline__ float tanh_f(float x) {
    float ax = fabsf(x);
    float t = __expf(-2.0f * ax);        // in (0,1], no overflow
    float r = (1.0f - t) / (1.0f + t);
    return copysignf(r, x);
}

// ---------------- prep: actual_W / actual_U, gate-interleaved ----------------
// out layout: a[k*1024 + j*4 + g] = orig[k*1024 + g*256 + j]
__global__ __launch_bounds__(256) void prep_kernel(
    const float* __restrict__ W,  const float* __restrict__ uW,
    const float* __restrict__ nW, const float* __restrict__ rW,
    const float* __restrict__ U,  const float* __restrict__ uU,
    const float* __restrict__ nU, const float* __restrict__ rU,
    float* __restrict__ aW4, float* __restrict__ aU4) {
    int idx = blockIdx.x * 256 + threadIdx.x;
    const int n = I_ * G4;  // 262144
    if (idx < n) {
        float v = W[idx] + masked_noise(uW[idx], nW[idx], rW[idx]);
        int k = idx >> 10, col = idx & 1023;
        int g = col >> 8, j = col & 255;
        aW4[((size_t)(k << 8) + j) * 4 + g] = v;
    } else {
        int i2 = idx - n;
        float v = U[i2] + masked_noise(uU[i2], nU[i2], rU[i2]);
        int k = i2 >> 10, col = i2 & 1023;
        int g = col >> 8, j = col & 255;
        aU4[((size_t)(k << 8) + j) * 4 + g] = v;
    }
}

// ---------------- xW = einsum('bsi,ig->sbg'), permuted columns ----------------
template<int XW_BF16>
__global__ __launch_bounds__(256) void xw_gemm(
    const float* __restrict__ x, const float* __restrict__ aW4,
    void* __restrict__ xw_out) {
    __shared__ float xs[64][132];  // [kk][row]
    __shared__ float wt[64][68];   // [kk][col]
    const int tid = threadIdx.x;
    const int tx = tid & 15;
    const int ty = tid >> 4;
    const int bx = blockIdx.x;
    const int s  = blockIdx.y;

    float acc[8][4];
#pragma unroll
    for (int i = 0; i < 8; ++i)
#pragma unroll
        for (int j = 0; j < 4; ++j) acc[i][j] = 0.0f;

    for (int kc = 0; kc < 4; ++kc) {
#pragma unroll
        for (int t = 0; t < 8; ++t) {
            int e = tid + t * 256;
            int row = e >> 4;
            int kq  = e & 15;
            float4 v = *reinterpret_cast<const float4*>(
                &x[((size_t)row * S_ + s) * I_ + kc * 64 + kq * 4]);
            xs[kq * 4 + 0][row] = v.x;
            xs[kq * 4 + 1][row] = v.y;
            xs[kq * 4 + 2][row] = v.z;
            xs[kq * 4 + 3][row] = v.w;
        }
#pragma unroll
        for (int t = 0; t < 4; ++t) {
            int e = tid + t * 256;
            int kk = e >> 4;
            int cq = e & 15;
            float4 v = *reinterpret_cast<const float4*>(
                &aW4[((size_t)(kc * 64 + kk)) * G4 + bx * 64 + cq * 4]);
            *reinterpret_cast<float4*>(&wt[kk][cq * 4]) = v;
        }
        __syncthreads();

#pragma unroll 8
        for (int kk = 0; kk < 64; ++kk) {
            float4 a0 = *reinterpret_cast<const float4*>(&xs[kk][ty * 8]);
            float4 a1 = *reinterpret_cast<const float4*>(&xs[kk][ty * 8 + 4]);
            float4 bv = *reinterpret_cast<const float4*>(&wt[kk][tx * 4]);
            float a[8] = {a0.x, a0.y, a0.z, a0.w, a1.x, a1.y, a1.z, a1.w};
            float b[4] = {bv.x, bv.y, bv.z, bv.w};
#pragma unroll
            for (int i = 0; i < 8; ++i)
#pragma unroll
                for (int j = 0; j < 4; ++j) acc[i][j] += a[i] * b[j];
        }
        __syncthreads();
    }

#pragma unroll
    for (int i = 0; i < 8; ++i) {
        int row = ty * 8 + i;
        size_t off = ((size_t)s * B_ + row) * G4 + bx * 64 + tx * 4;
        if (XW_BF16) {
            __hip_bfloat16* xwb = (__hip_bfloat16*)xw_out;
            alignas(8) __hip_bfloat16 tmp[4];
#pragma unroll
            for (int j = 0; j < 4; ++j) tmp[j] = __float2bfloat16(acc[i][j]);
            *reinterpret_cast<ushort4*>(&xwb[off]) =
                *reinterpret_cast<const ushort4*>(tmp);
        } else {
            float* xwf = (float*)xw_out;
            float4 v = {acc[i][0], acc[i][1], acc[i][2], acc[i][3]};
            *reinterpret_cast<float4*>(&xwf[off]) = v;
        }
    }
}

// ---------------- sequential LSTM scan, 4-way split-k ----------------
// 64 blocks x 1024 threads. Block owns batches {2*bid, 2*bid+1}.
// Thread (u=tid&255, kq=tid>>8): partial i,f,g,o sums for BOTH batches over
// k in [kq*64, kq*64+64). kq==0 threads reduce + activate + hold c,h.
// TIER: 0 = fp32 xw, 1 = bf16 xw, 2 = fused (recompute x@W per step).
template<int TIER>
__global__ __launch_bounds__(1024) void lstm_scan(
    const void* __restrict__ xw_in, const float* __restrict__ aU4,
    const float* __restrict__ aW4, const float* __restrict__ x,
    float* __restrict__ out) {
    const int tid = threadIdx.x;
    const int u   = tid & 255;
    const int kq  = tid >> 8;               // 0..3
    const int b0  = blockIdx.x * 2;

    __shared__ float hbuf[2][H_][2];        // [buf][k][bb]      4 KB
    __shared__ float part[2][3][8][256];    // [buf][kq-1][slot][u] 48 KB
    __shared__ float xsh[I_][2];            // TIER2 x rows       2 KB

    if (tid < 512) hbuf[0][tid & 255][tid >> 8] = 0.0f;
    float c0 = 0.f, c1 = 0.f, h0 = 0.f, h1 = 0.f;   // kq==0 only
    __syncthreads();

    const float*          xwf = (const float*)xw_in;
    const __hip_bfloat16* xwb = (const __hip_bfloat16*)xw_in;
    const float* Ub = aU4 + ((size_t)kq * 64) * G4 + ((size_t)u << 2);
    const float* Wb = aW4 + ((size_t)kq * 64) * G4 + ((size_t)u << 2);

    for (int s = 0; s < S_; ++s) {
        const int cur = s & 1;

        if (TIER == 2) {
            if (tid < 512)
                xsh[tid & 255][tid >> 8] =
                    x[((size_t)(b0 + (tid >> 8)) * S_ + s) * I_ + (tid & 255)];
            __syncthreads();
        }

        // issue xw loads early (consumed after barrier)
        float4 xg0 = {0.f, 0.f, 0.f, 0.f}, xg1 = {0.f, 0.f, 0.f, 0.f};
        if (TIER == 0 && kq == 0) {
            size_t xoff = ((size_t)s * B_ + b0) * G4 + ((size_t)u << 2);
            xg0 = *reinterpret_cast<const float4*>(&xwf[xoff]);
            xg1 = *reinterpret_cast<const float4*>(&xwf[xoff + G4]);
        } else if (TIER == 1 && kq == 0) {
            size_t xoff = ((size_t)s * B_ + b0) * G4 + ((size_t)u << 2);
            ushort4 r0 = *reinterpret_cast<const ushort4*>(&xwb[xoff]);
            ushort4 r1 = *reinterpret_cast<const ushort4*>(&xwb[xoff + G4]);
            xg0.x = __uint_as_float((unsigned)r0.x << 16);
            xg0.y = __uint_as_float((unsigned)r0.y << 16);
            xg0.z = __uint_as_float((unsigned)r0.z << 16);
            xg0.w = __uint_as_float((unsigned)r0.w << 16);
            xg1.x = __uint_as_float((unsigned)r1.x << 16);
            xg1.y = __uint_as_float((unsigned)r1.y << 16);
            xg1.z = __uint_as_float((unsigned)r1.z << 16);
            xg1.w = __uint_as_float((unsigned)r1.w << 16);
        }

        float a00 = 0.f, a01 = 0.f, a02 = 0.f, a03 = 0.f;   // batch b0
        float a10 = 0.f, a11 = 0.f, a12 = 0.f, a13 = 0.f;   // batch b0+1

#pragma unroll 8
        for (int kk = 0; kk < 64; ++kk) {
            float2 h2 = *reinterpret_cast<const float2*>(
                &hbuf[cur][kq * 64 + kk][0]);
            float4 uv = *reinterpret_cast<const float4*>(
                &Ub[(size_t)kk * G4]);
            a00 += h2.x * uv.x; a01 += h2.x * uv.y;
            a02 += h2.x * uv.z; a03 += h2.x * uv.w;
            a10 += h2.y * uv.x; a11 += h2.y * uv.y;
            a12 += h2.y * uv.z; a13 += h2.y * uv.w;
            if (TIER == 2) {
                float2 x2 = *reinterpret_cast<const float2*>(
                    &xsh[kq * 64 + kk][0]);
                float4 wv = *reinterpret_cast<const float4*>(
                    &Wb[(size_t)kk * G4]);
                a00 += x2.x * wv.x; a01 += x2.x * wv.y;
                a02 += x2.x * wv.z; a03 += x2.x * wv.w;
                a10 += x2.y * wv.x; a11 += x2.y * wv.y;
                a12 += x2.y * wv.z; a13 += x2.y * wv.w;
            }
        }

        if (kq > 0) {
            float (*p)[256] = part[cur][kq - 1];
            p[0][u] = a00; p[1][u] = a01; p[2][u] = a02; p[3][u] = a03;
            p[4][u] = a10; p[5][u] = a11; p[6][u] = a12; p[7][u] = a13;
        }
        __syncthreads();

        if (kq == 0) {
#pragma unroll
            for (int q = 0; q < 3; ++q) {
                float (*p)[256] = part[cur][q];
                a00 += p[0][u]; a01 += p[1][u]; a02 += p[2][u]; a03 += p[3][u];
                a10 += p[4][u]; a11 += p[5][u]; a12 += p[6][u]; a13 += p[7][u];
            }
            float it = sigmoid_f(a00 + xg0.x);
            float ft = sigmoid_f(a01 + xg0.y);
            float gt = tanh_f(a02 + xg0.z);
            float ot = sigmoid_f(a03 + xg0.w);
            c0 = ft * c0 + it * gt;
            h0 = ot * tanh_f(c0);

            it = sigmoid_f(a10 + xg1.x);
            ft = sigmoid_f(a11 + xg1.y);
            gt = tanh_f(a12 + xg1.z);
            ot = sigmoid_f(a13 + xg1.w);
            c1 = ft * c1 + it * gt;
            h1 = ot * tanh_f(c1);

            out[((size_t)b0 * S_ + s) * H_ + u]       = h0;
            out[((size_t)(b0 + 1) * S_ + s) * H_ + u] = h1;
            hbuf[cur ^ 1][u][0] = h0;
            hbuf[cur ^ 1][u][1] = h1;
        }
        __syncthreads();
    }

    if (kq == 0) {
        const size_t HS = (size_t)B_ * S_ * H_;      // 16777216
        const size_t CS = (size_t)B_ * H_;           // 32768
        out[HS + (size_t)b0 * H_ + u]            = h0;
        out[HS + (size_t)(b0 + 1) * H_ + u]      = h1;
        out[HS + CS + (size_t)b0 * H_ + u]       = c0;
        out[HS + CS + (size_t)(b0 + 1) * H_ + u] = c1;
    }
}

// ---------------- launch ----------------
extern "C" void kernel_launch(void* const* d_in, const int* in_sizes, int n_in,
                              void* d_out, int out_size, void* d_ws, size_t ws_size,
                              hipStream_t stream) {
    const float* x  = (const float*)d_in[0];
    const float* W  = (const float*)d_in[1];
    const float* U  = (const float*)d_in[2];
    const float* uW = (const float*)d_in[3];
    const float* nW = (const float*)d_in[4];
    const float* rW = (const float*)d_in[5];
    const float* uU = (const float*)d_in[6];
    const float* nU = (const float*)d_in[7];
    const float* rU = (const float*)d_in[8];

    float* ws  = (float*)d_ws;
    float* aW4 = ws;                       // 262144 floats
    float* aU4 = ws + 262144;              // 262144 floats
    void*  xw  = (void*)(ws + 524288);     // S*B*4H elems (fp32 or bf16)

    const size_t xw_elems  = (size_t)S_ * B_ * G4;            // 67108864
    const size_t need_fp32 = (524288 + xw_elems) * 4;         // ~258 MB
    const size_t need_bf16 = 524288 * 4 + xw_elems * 2;       // ~130 MB

    prep_kernel<<<2048, 256, 0, stream>>>(W, uW, nW, rW, U, uU, nU, rU, aW4, aU4);

    dim3 ggrid(16, 512);
    if (ws_size >= need_fp32) {
        xw_gemm<0><<<ggrid, 256, 0, stream>>>(x, aW4, xw);
        lstm_scan<0><<<64, 1024, 0, stream>>>(xw, aU4, aW4, x, (float*)d_out);
    } else if (ws_size >= need_bf16) {
        xw_gemm<1><<<ggrid, 256, 0, stream>>>(x, aW4, xw);
        lstm_scan<1><<<64, 1024, 0, stream>>>(xw, aU4, aW4, x, (float*)d_out);
    } else {
        lstm_scan<2><<<64, 1024, 0, stream>>>(nullptr, aU4, aW4, x, (float*)d_out);
    }
}